// Round 14
// baseline (1967.429 us; speedup 1.0000x reference)
//
#include <hip/hip_runtime.h>
#include <hip/hip_bf16.h>
#include <cstdint>
#include <cstddef>

#define NB 4
#define NPTS 4096
#define KK 20

typedef unsigned int u32;
typedef unsigned long long u64;

__device__ __forceinline__ float lrelu(float v) { return v >= 0.f ? v : 0.2f * v; }

// monotone map: larger float -> larger u32 (total order, handles negatives)
__device__ __forceinline__ u32 fmap(float f) {
  u32 u = __float_as_uint(f);
  return (int)u < 0 ? ~u : (u | 0x80000000u);
}

__device__ __forceinline__ u64 wmax64(u64 v) {
#pragma unroll
  for (int o = 32; o >= 1; o >>= 1) {
    u64 t = __shfl_xor(v, o, 64);
    v = t > v ? t : v;
  }
  return v;
}

// ---------------- squared norms ----------------
template <int C>
__global__ void k_sq(const float* __restrict__ f, float* __restrict__ xx) {
  int p = blockIdx.x * 256 + threadIdx.x;
  const float* fp = f + (size_t)p * C;
  float s = 0.f;
  if constexpr ((C & 3) == 0) {
#pragma unroll
    for (int c = 0; c < C; c += 4) {
      float4 v = *reinterpret_cast<const float4*>(fp + c);
      s += v.x * v.x + v.y * v.y + v.z * v.z + v.w * v.w;
    }
  } else {
#pragma unroll
    for (int c = 0; c < C; c++) s += fp[c] * fp[c];
  }
  xx[p] = s;
}

// ---------------- knn C=6: 8 waves/block, one row per wave ----------------
__global__ __launch_bounds__(512) void k_knn6(const float* __restrict__ f,
                                              const float* __restrict__ xx,
                                              int* __restrict__ idxo,
                                              int* __restrict__ flg) {
  __shared__ float chunkl[6 * 65];
  const int tid = threadIdx.x, wv = tid >> 6, lane = tid & 63;
  const int row = blockIdx.x * 8 + wv;
  const int b = row >> 12;
  const float xi = xx[row];

  float y[6];
#pragma unroll
  for (int c = 0; c < 6; c++) y[c] = f[(size_t)row * 6 + c];

  u64 t0 = 0, t1 = 0, t2 = 0, t3 = 0;

  for (int jc = 0; jc < NPTS / 64; jc++) {
    __syncthreads();
    for (int t = tid; t < 64 * 6; t += 512) {
      int j = t / 6, c = t - j * 6;
      chunkl[c * 65 + j] = f[(size_t)(b * NPTS + jc * 64 + j) * 6 + c];
    }
    __syncthreads();
    const float xj = xx[b * NPTS + jc * 64 + lane];
    float acc = 0.f;
#pragma unroll
    for (int c = 0; c < 6; c++) acc = fmaf(chunkl[c * 65 + lane], y[c], acc);
    const float s = fmaf(2.f, acc, -xi) - xj;
    const u64 key = ((u64)fmap(s) << 32) | (u64)(~(u32)(jc * 64 + lane));
    if (key > t3) {
      u64 a0 = t0, a1 = t1, a2 = t2;
      bool g0 = key > a0, g1 = key > a1, g2 = key > a2;
      t0 = g0 ? key : a0;
      t1 = g0 ? a0 : (g1 ? key : a1);
      t2 = g1 ? a1 : (g2 ? key : a2);
      t3 = g2 ? a2 : key;
    }
  }

  u64 h = t0, n1 = t1, n2 = t2, n3 = t3;
  int pops = 0, myj = 0;
  for (int m = 0; m < KK; m++) {
    u64 wm = wmax64(h);
    int j = (int)(~(u32)wm) & (NPTS - 1);
    if (lane == m) myj = j;
    if (h == wm) { h = n1; n1 = n2; n2 = n3; n3 = 0; pops++; }
  }
  u64 bad = __ballot(pops >= 4);
  if (lane < KK) idxo[(size_t)row * KK + lane] = myj;
  if (lane == 0) flg[row] = (bad != 0ull) ? 1 : 0;
}

// ---------------- knn C=64 v13: 2-chunk LDS, 8 waves/SIMD -------------------
// r13 post-mortem: v11/v12 plateau ~295us at 4 waves/SIMD, VALUBusy 73%,
// VGPR 60 -- just under the 64-VGPR occupancy boundary (m69: waves/CU halve
// at 64/128/256). v13 exploits it: 2 candidate chunks (LDS 34.8KB -> 4
// blocks/CU x 8 waves = 32 waves/CU = 8 waves/SIMD, 2x TLP) with
// acc[4][2] (8 VGPR less than v12 -> ~52). __launch_bounds__(512,4) caps
// VGPR at 64. Per q: 2 cand b128 LDS + 4 y global(wave-uniform, L1-hot)
// per 32 FMAs. Selection stream per (lane,row) unchanged (2/chunk-pair x
// 32 = 64 candidates); sorted top-4 cache + pops>=4 flag + exact fallback.
// Revert trigger: WRITE_SIZE explosion = spill under the 64-cap (r7 mode).
__global__ __launch_bounds__(512, 4) void k_knn64(const float* __restrict__ f,
                                                  const float* __restrict__ xx,
                                                  int* __restrict__ idxo,
                                                  int* __restrict__ flg) {
  __shared__ float ch[2][64 * 68];
  const int tid = threadIdx.x, wv = tid >> 6, lane = tid & 63;
  const int rowbase = blockIdx.x * 32;
  const int b = rowbase >> 12;
  const float* fb = f + (size_t)b * NPTS * 64;
  const int r0 = rowbase + wv * 4;
  const float* yrow = f + (size_t)r0 * 64;  // 4 contiguous rows, wave-uniform

  float xi[4];
#pragma unroll
  for (int r = 0; r < 4; r++) xi[r] = xx[r0 + r];

  u64 t0[4], t1[4], t2[4], t3[4];
#pragma unroll
  for (int r = 0; r < 4; r++) { t0[r] = 0; t1[r] = 0; t2[r] = 0; t3[r] = 0; }

#pragma unroll 1
  for (int jp = 0; jp < NPTS / 128; jp++) {
    // stage pair (128 candidates x 64 ch): 4 float4 per thread
#pragma unroll 1
    for (int k = 0; k < 4; k++) {
      int flat = k * 512 + tid;  // 0..2047 float4s
      int row = flat >> 4, q = flat & 15;
      float4 v = *reinterpret_cast<const float4*>(
          fb + (size_t)(jp * 128 + row) * 64 + 4 * q);
      *reinterpret_cast<float4*>(&ch[row >> 6][(row & 63) * 68 + 4 * q]) = v;
    }
    __syncthreads();

    float acc[4][2];
#pragma unroll
    for (int r = 0; r < 4; r++) { acc[r][0] = 0.f; acc[r][1] = 0.f; }
#pragma unroll 2
    for (int q = 0; q < 16; q++) {
      const float4 c0 = *reinterpret_cast<const float4*>(&ch[0][lane * 68 + 4 * q]);
      const float4 c1 = *reinterpret_cast<const float4*>(&ch[1][lane * 68 + 4 * q]);
#pragma unroll
      for (int r = 0; r < 4; r++) {
        const float4 yq = *reinterpret_cast<const float4*>(yrow + r * 64 + 4 * q);
        acc[r][0] = fmaf(c0.x, yq.x, acc[r][0]);
        acc[r][0] = fmaf(c0.y, yq.y, acc[r][0]);
        acc[r][0] = fmaf(c0.z, yq.z, acc[r][0]);
        acc[r][0] = fmaf(c0.w, yq.w, acc[r][0]);
        acc[r][1] = fmaf(c1.x, yq.x, acc[r][1]);
        acc[r][1] = fmaf(c1.y, yq.y, acc[r][1]);
        acc[r][1] = fmaf(c1.z, yq.z, acc[r][1]);
        acc[r][1] = fmaf(c1.w, yq.w, acc[r][1]);
      }
    }
    const float xj0 = xx[b * NPTS + jp * 128 + lane];
    const float xj1 = xx[b * NPTS + jp * 128 + 64 + lane];
    const u32 j0 = ~(u32)(jp * 128 + lane);
    const u32 j1 = ~(u32)(jp * 128 + 64 + lane);
#pragma unroll
    for (int r = 0; r < 4; r++) {
      {
        const float s = fmaf(2.f, acc[r][0], -xi[r]) - xj0;
        const u64 key = ((u64)fmap(s) << 32) | (u64)j0;
        if (key > t3[r]) {
          u64 a0 = t0[r], a1 = t1[r], a2 = t2[r];
          bool g0 = key > a0, g1 = key > a1, g2 = key > a2;
          t0[r] = g0 ? key : a0;
          t1[r] = g0 ? a0 : (g1 ? key : a1);
          t2[r] = g1 ? a1 : (g2 ? key : a2);
          t3[r] = g2 ? a2 : key;
        }
      }
      {
        const float s = fmaf(2.f, acc[r][1], -xi[r]) - xj1;
        const u64 key = ((u64)fmap(s) << 32) | (u64)j1;
        if (key > t3[r]) {
          u64 a0 = t0[r], a1 = t1[r], a2 = t2[r];
          bool g0 = key > a0, g1 = key > a1, g2 = key > a2;
          t0[r] = g0 ? key : a0;
          t1[r] = g0 ? a0 : (g1 ? key : a1);
          t2[r] = g1 ? a1 : (g2 ? key : a2);
          t3[r] = g2 ? a2 : key;
        }
      }
    }
    __syncthreads();
  }

#pragma unroll
  for (int r = 0; r < 4; r++) {
    u64 h = t0[r], n1 = t1[r], n2 = t2[r], n3 = t3[r];
    int pops = 0, myj = 0;
    for (int m = 0; m < KK; m++) {
      u64 wm = wmax64(h);
      int j = (int)(~(u32)wm) & (NPTS - 1);
      if (lane == m) myj = j;
      if (h == wm) { h = n1; n1 = n2; n2 = n3; n3 = 0; pops++; }
    }
    u64 bad = __ballot(pops >= 4);
    if (lane < KK) idxo[(size_t)(r0 + r) * KK + lane] = myj;
    if (lane == 0) flg[r0 + r] = (bad != 0ull) ? 1 : 0;
  }
}

// rare exact fallback for flagged rows
template <int C>
__global__ __launch_bounds__(64) void k_knn_fix(const float* __restrict__ f,
                                                const float* __restrict__ xx,
                                                int* __restrict__ idxo,
                                                const int* __restrict__ flg) {
  __shared__ u64 kl[NPTS];
  const int lane = threadIdx.x;
  for (int row = blockIdx.x; row < NB * NPTS; row += gridDim.x) {
    if (!flg[row]) continue;
    const int b = row >> 12;
    float yreg[C];
#pragma unroll
    for (int c = 0; c < C; c++) yreg[c] = f[(size_t)row * C + c];
    const float xi = xx[row];
    for (int jj = 0; jj < 64; jj++) {
      int j = jj * 64 + lane;
      const float* fp = f + (size_t)(b * NPTS + j) * C;
      float d = 0.f;
#pragma unroll
      for (int c = 0; c < C; c++) d = fmaf(yreg[c], fp[c], d);
      float s = fmaf(2.f, d, -xi) - xx[b * NPTS + j];
      kl[j] = ((u64)fmap(s) << 32) | (u64)(u32)(~(u32)j);
    }
    __syncthreads();
    int myj = 0;
    for (int m = 0; m < KK; m++) {
      u64 lm = 0;
      for (int jj = 0; jj < 64; jj++) {
        u64 v = kl[jj * 64 + lane];
        lm = v > lm ? v : lm;
      }
      u64 wm = wmax64(lm);
      int j = (int)(~(u32)wm) & (NPTS - 1);
      if (lane == m) myj = j;
      if (lane == (j & 63)) kl[j] = 0;
      __syncthreads();
    }
    if (lane < KK) idxo[row * KK + lane] = myj;
    __syncthreads();
  }
}

// ---------------- edgeconv stage 1: 6 -> (12) -> 64 -> 64, max over K -------
// r13: 4 accumulation chains (dep latency halved) + next-k neighbor prefetch.
__global__ __launch_bounds__(256) void k_ec1(
    const float* __restrict__ x, const int* __restrict__ idx,
    const float* __restrict__ w1, const float* __restrict__ s1, const float* __restrict__ b1,
    const float* __restrict__ w2, const float* __restrict__ s2, const float* __restrict__ b2,
    float* __restrict__ out) {
  __shared__ float h1l[4][64];
  const int wv = threadIdx.x >> 6, lane = threadIdx.x & 63;
  float w1r[12];
#pragma unroll
  for (int c = 0; c < 12; c += 4) {
    float4 v = *reinterpret_cast<const float4*>(w1 + lane * 12 + c);
    w1r[c] = v.x; w1r[c + 1] = v.y; w1r[c + 2] = v.z; w1r[c + 3] = v.w;
  }
  float w2r[64];
#pragma unroll
  for (int c = 0; c < 64; c += 4) {
    float4 v = *reinterpret_cast<const float4*>(w2 + lane * 64 + c);
    w2r[c] = v.x; w2r[c + 1] = v.y; w2r[c + 2] = v.z; w2r[c + 3] = v.w;
  }
  const float sc1 = s1[lane], bc1 = b1[lane], sc2 = s2[lane], bc2 = b2[lane];
  const int wid = blockIdx.x * 4 + wv;
  for (int p = wid; p < NB * NPTS; p += 2048) {
    const float* cp = x + (size_t)p * 6;
    float c0 = cp[0], c1 = cp[1], c2 = cp[2], c3 = cp[3], c4 = cp[4], c5 = cp[5];
    const int bb = p >> 12;
    float m = -3.402823466e38f;
    int nb = idx[p * KK];
    float n0v[6];
    {
      const float* nf = x + (size_t)((bb << 12) + nb) * 6;
#pragma unroll
      for (int c = 0; c < 6; c++) n0v[c] = nf[c];
    }
    for (int k = 0; k < KK; k++) {
      float e0 = n0v[0] - c0, e1 = n0v[1] - c1, e2 = n0v[2] - c2;
      float e3 = n0v[3] - c3, e4 = n0v[4] - c4, e5 = n0v[5] - c5;
      if (k + 1 < KK) {
        int nb2 = idx[p * KK + k + 1];
        const float* nf = x + (size_t)((bb << 12) + nb2) * 6;
#pragma unroll
        for (int c = 0; c < 6; c++) n0v[c] = nf[c];
      }
      float h = w1r[0] * e0 + w1r[1] * e1 + w1r[2] * e2 + w1r[3] * e3 + w1r[4] * e4 +
                w1r[5] * e5 + w1r[6] * c0 + w1r[7] * c1 + w1r[8] * c2 + w1r[9] * c3 +
                w1r[10] * c4 + w1r[11] * c5;
      h = lrelu(fmaf(h, sc1, bc1));
      h1l[wv][lane] = h;
      float a0 = 0.f, a1 = 0.f, a2 = 0.f, a3 = 0.f;
#pragma unroll
      for (int c = 0; c < 64; c += 16) {
        float4 h0 = *reinterpret_cast<const float4*>(&h1l[wv][c]);
        float4 h1 = *reinterpret_cast<const float4*>(&h1l[wv][c + 4]);
        float4 h2 = *reinterpret_cast<const float4*>(&h1l[wv][c + 8]);
        float4 h3 = *reinterpret_cast<const float4*>(&h1l[wv][c + 12]);
        a0 = fmaf(w2r[c], h0.x, a0); a0 = fmaf(w2r[c + 1], h0.y, a0);
        a0 = fmaf(w2r[c + 2], h0.z, a0); a0 = fmaf(w2r[c + 3], h0.w, a0);
        a1 = fmaf(w2r[c + 4], h1.x, a1); a1 = fmaf(w2r[c + 5], h1.y, a1);
        a1 = fmaf(w2r[c + 6], h1.z, a1); a1 = fmaf(w2r[c + 7], h1.w, a1);
        a2 = fmaf(w2r[c + 8], h2.x, a2); a2 = fmaf(w2r[c + 9], h2.y, a2);
        a2 = fmaf(w2r[c + 10], h2.z, a2); a2 = fmaf(w2r[c + 11], h2.w, a2);
        a3 = fmaf(w2r[c + 12], h3.x, a3); a3 = fmaf(w2r[c + 13], h3.y, a3);
        a3 = fmaf(w2r[c + 14], h3.z, a3); a3 = fmaf(w2r[c + 15], h3.w, a3);
      }
      m = fmaxf(m, lrelu(fmaf((a0 + a1) + (a2 + a3), sc2, bc2)));
    }
    out[(size_t)p * 64 + lane] = m;
  }
}

// ---------------- edgeconv stages 2/3: 64 -> (128) -> 64 [-> 64], max over K
// r13: 4 accumulation chains + next-k neighbor-feature prefetch.
template <bool HAS2>
__global__ __launch_bounds__(256, 1) void k_ec2(
    const float* __restrict__ xin, const int* __restrict__ idx,
    const float* __restrict__ w3, const float* __restrict__ s3, const float* __restrict__ b3,
    const float* __restrict__ w4, const float* __restrict__ s4, const float* __restrict__ b4,
    float* __restrict__ out) {
  __shared__ float ctl[4][64];
  __shared__ float nbl[4][64];
  __shared__ float h1l[4][64];
  const int wv = threadIdx.x >> 6, lane = threadIdx.x & 63;
  float wa[64], wb[64];
#pragma unroll
  for (int c = 0; c < 64; c += 4) {
    float4 va = *reinterpret_cast<const float4*>(w3 + (size_t)lane * 128 + c);
    float4 vb = *reinterpret_cast<const float4*>(w3 + (size_t)lane * 128 + 64 + c);
    wa[c] = va.x; wa[c + 1] = va.y; wa[c + 2] = va.z; wa[c + 3] = va.w;
    wb[c] = vb.x - va.x; wb[c + 1] = vb.y - va.y; wb[c + 2] = vb.z - va.z; wb[c + 3] = vb.w - va.w;
  }
  float w4r[64];
  if constexpr (HAS2) {
#pragma unroll
    for (int c = 0; c < 64; c += 4) {
      float4 v = *reinterpret_cast<const float4*>(w4 + (size_t)lane * 64 + c);
      w4r[c] = v.x; w4r[c + 1] = v.y; w4r[c + 2] = v.z; w4r[c + 3] = v.w;
    }
  }
  const float sc3 = s3[lane], bc3 = b3[lane];
  float sc4 = 0.f, bc4 = 0.f;
  if constexpr (HAS2) { sc4 = s4[lane]; bc4 = b4[lane]; }
  const int wid = blockIdx.x * 4 + wv;
  for (int p = wid; p < NB * NPTS; p += 2048) {
    const int bb = p >> 12;
    ctl[wv][lane] = xin[(size_t)p * 64 + lane];
    float d0 = 0.f, d1 = 0.f;
#pragma unroll
    for (int c = 0; c < 64; c += 8) {
      float4 cv = *reinterpret_cast<const float4*>(&ctl[wv][c]);
      float4 cw = *reinterpret_cast<const float4*>(&ctl[wv][c + 4]);
      d0 = fmaf(wb[c], cv.x, d0); d0 = fmaf(wb[c + 1], cv.y, d0);
      d0 = fmaf(wb[c + 2], cv.z, d0); d0 = fmaf(wb[c + 3], cv.w, d0);
      d1 = fmaf(wb[c + 4], cw.x, d1); d1 = fmaf(wb[c + 5], cw.y, d1);
      d1 = fmaf(wb[c + 6], cw.z, d1); d1 = fmaf(wb[c + 7], cw.w, d1);
    }
    const float cd = d0 + d1;
    float m = -3.402823466e38f;
    float cur = xin[(size_t)((bb << 12) + idx[p * KK]) * 64 + lane];
    for (int k = 0; k < KK; k++) {
      nbl[wv][lane] = cur;
      if (k + 1 < KK)
        cur = xin[(size_t)((bb << 12) + idx[p * KK + k + 1]) * 64 + lane];
      float a0 = cd, a1 = 0.f, a2 = 0.f, a3 = 0.f;
#pragma unroll
      for (int c = 0; c < 64; c += 16) {
        float4 n0 = *reinterpret_cast<const float4*>(&nbl[wv][c]);
        float4 n1 = *reinterpret_cast<const float4*>(&nbl[wv][c + 4]);
        float4 n2 = *reinterpret_cast<const float4*>(&nbl[wv][c + 8]);
        float4 n3 = *reinterpret_cast<const float4*>(&nbl[wv][c + 12]);
        a0 = fmaf(wa[c], n0.x, a0); a0 = fmaf(wa[c + 1], n0.y, a0);
        a0 = fmaf(wa[c + 2], n0.z, a0); a0 = fmaf(wa[c + 3], n0.w, a0);
        a1 = fmaf(wa[c + 4], n1.x, a1); a1 = fmaf(wa[c + 5], n1.y, a1);
        a1 = fmaf(wa[c + 6], n1.z, a1); a1 = fmaf(wa[c + 7], n1.w, a1);
        a2 = fmaf(wa[c + 8], n2.x, a2); a2 = fmaf(wa[c + 9], n2.y, a2);
        a2 = fmaf(wa[c + 10], n2.z, a2); a2 = fmaf(wa[c + 11], n2.w, a2);
        a3 = fmaf(wa[c + 12], n3.x, a3); a3 = fmaf(wa[c + 13], n3.y, a3);
        a3 = fmaf(wa[c + 14], n3.z, a3); a3 = fmaf(wa[c + 15], n3.w, a3);
      }
      float h = lrelu(fmaf((a0 + a1) + (a2 + a3), sc3, bc3));
      if constexpr (HAS2) {
        h1l[wv][lane] = h;
        float q0 = 0.f, q1 = 0.f, q2 = 0.f, q3 = 0.f;
#pragma unroll
        for (int c = 0; c < 64; c += 16) {
          float4 h0 = *reinterpret_cast<const float4*>(&h1l[wv][c]);
          float4 h1 = *reinterpret_cast<const float4*>(&h1l[wv][c + 4]);
          float4 h2 = *reinterpret_cast<const float4*>(&h1l[wv][c + 8]);
          float4 h3 = *reinterpret_cast<const float4*>(&h1l[wv][c + 12]);
          q0 = fmaf(w4r[c], h0.x, q0); q0 = fmaf(w4r[c + 1], h0.y, q0);
          q0 = fmaf(w4r[c + 2], h0.z, q0); q0 = fmaf(w4r[c + 3], h0.w, q0);
          q1 = fmaf(w4r[c + 4], h1.x, q1); q1 = fmaf(w4r[c + 5], h1.y, q1);
          q1 = fmaf(w4r[c + 6], h1.z, q1); q1 = fmaf(w4r[c + 7], h1.w, q1);
          q2 = fmaf(w4r[c + 8], h2.x, q2); q2 = fmaf(w4r[c + 9], h2.y, q2);
          q2 = fmaf(w4r[c + 10], h2.z, q2); q2 = fmaf(w4r[c + 11], h2.w, q2);
          q3 = fmaf(w4r[c + 12], h3.x, q3); q3 = fmaf(w4r[c + 13], h3.y, q3);
          q3 = fmaf(w4r[c + 14], h3.z, q3); q3 = fmaf(w4r[c + 15], h3.w, q3);
        }
        m = fmaxf(m, lrelu(fmaf((q0 + q1) + (q2 + q3), sc4, bc4)));
      } else {
        m = fmaxf(m, h);
      }
    }
    out[(size_t)p * 64 + lane] = m;
  }
}

// ---------------- conv6 v2: conv8-style tiled GEMM + max epilogue -----------
__global__ __launch_bounds__(256) void k_conv6(
    const float* __restrict__ x1, const float* __restrict__ x2, const float* __restrict__ x3,
    const float* __restrict__ w6, const float* __restrict__ s6, const float* __restrict__ b6,
    float* __restrict__ gpart) {
  __shared__ float Wl[64 * 68];
  __shared__ float Xl[64 * 68];
  __shared__ float mxl[16][64];
  const int tid = threadIdx.x;
  const int cot = blockIdx.x & 15;  // 16 co-tiles of 64
  const int ptb = blockIdx.x >> 4;  // 0..127, 128 pts each
  const int co0 = (tid & 15) * 4;
  const int n0 = (tid >> 4) * 4;
  const int sr = tid >> 2;
  const int sci = (tid & 3) * 16;
  float scv[4], bcv[4];
#pragma unroll
  for (int i = 0; i < 4; i++) {
    scv[i] = s6[cot * 64 + co0 + i];
    bcv[i] = b6[cot * 64 + co0 + i];
  }
  float mx[4];
#pragma unroll
  for (int i = 0; i < 4; i++) mx[i] = -3.402823466e38f;

  for (int half = 0; half < 2; half++) {
    float acc[4][4];
#pragma unroll
    for (int i = 0; i < 4; i++)
#pragma unroll
      for (int j = 0; j < 4; j++) acc[i][j] = 0.f;
    for (int cib = 0; cib < 3; cib++) {
      const float* xsel = cib == 0 ? x1 : cib == 1 ? x2 : x3;
      __syncthreads();
      {
        const float* ws_ = w6 + (size_t)(cot * 64 + sr) * 192 + cib * 64 + sci;
#pragma unroll
        for (int s = 0; s < 16; s += 4) {
          float4 v = *reinterpret_cast<const float4*>(ws_ + s);
          Wl[(sci + s) * 68 + sr] = v.x;
          Wl[(sci + s + 1) * 68 + sr] = v.y;
          Wl[(sci + s + 2) * 68 + sr] = v.z;
          Wl[(sci + s + 3) * 68 + sr] = v.w;
        }
        const float* xs = xsel + (size_t)(ptb * 128 + half * 64 + sr) * 64 + sci;
#pragma unroll
        for (int s = 0; s < 16; s += 4) {
          float4 v = *reinterpret_cast<const float4*>(xs + s);
          Xl[(sci + s) * 68 + sr] = v.x;
          Xl[(sci + s + 1) * 68 + sr] = v.y;
          Xl[(sci + s + 2) * 68 + sr] = v.z;
          Xl[(sci + s + 3) * 68 + sr] = v.w;
        }
      }
      __syncthreads();
#pragma unroll 8
      for (int ci = 0; ci < 64; ci++) {
        float4 wv = *reinterpret_cast<const float4*>(&Wl[ci * 68 + co0]);
        float4 xv = *reinterpret_cast<const float4*>(&Xl[ci * 68 + n0]);
        acc[0][0] = fmaf(wv.x, xv.x, acc[0][0]);
        acc[0][1] = fmaf(wv.x, xv.y, acc[0][1]);
        acc[0][2] = fmaf(wv.x, xv.z, acc[0][2]);
        acc[0][3] = fmaf(wv.x, xv.w, acc[0][3]);
        acc[1][0] = fmaf(wv.y, xv.x, acc[1][0]);
        acc[1][1] = fmaf(wv.y, xv.y, acc[1][1]);
        acc[1][2] = fmaf(wv.y, xv.z, acc[1][2]);
        acc[1][3] = fmaf(wv.y, xv.w, acc[1][3]);
        acc[2][0] = fmaf(wv.z, xv.x, acc[2][0]);
        acc[2][1] = fmaf(wv.z, xv.y, acc[2][1]);
        acc[2][2] = fmaf(wv.z, xv.z, acc[2][2]);
        acc[2][3] = fmaf(wv.z, xv.w, acc[2][3]);
        acc[3][0] = fmaf(wv.w, xv.x, acc[3][0]);
        acc[3][1] = fmaf(wv.w, xv.y, acc[3][1]);
        acc[3][2] = fmaf(wv.w, xv.z, acc[3][2]);
        acc[3][3] = fmaf(wv.w, xv.w, acc[3][3]);
      }
    }
#pragma unroll
    for (int i = 0; i < 4; i++)
#pragma unroll
      for (int j = 0; j < 4; j++)
        mx[i] = fmaxf(mx[i], lrelu(fmaf(acc[i][j], scv[i], bcv[i])));
  }
  __syncthreads();
#pragma unroll
  for (int i = 0; i < 4; i++) mxl[tid >> 4][co0 + i] = mx[i];
  __syncthreads();
  if (tid < 64) {
    float m = -3.402823466e38f;
#pragma unroll
    for (int g = 0; g < 16; g++) m = fmaxf(m, mxl[g][tid]);
    const int b = ptb >> 5, ch = ptb & 31;
    gpart[(size_t)(b * 32 + ch) * 1024 + cot * 64 + tid] = m;
  }
}

__global__ void k_gred(const float* __restrict__ gpart, float* __restrict__ g) {
  int t = blockIdx.x * 256 + threadIdx.x;
  int b = t >> 10, co = t & 1023;
  float m = -3.402823466e38f;
  for (int ch = 0; ch < 32; ch++) m = fmaxf(m, gpart[(size_t)(b * 32 + ch) * 1024 + co]);
  g[t] = m;
}

// gc[b][co] = sum_{ci<1024} w7[co][ci] * g[b][ci]; 64 blocks, 8-way ci split
__global__ __launch_bounds__(256) void k_gc(const float* __restrict__ w7,
                                            const float* __restrict__ g,
                                            float* __restrict__ gcv) {
  __shared__ float red[256];
  const int tid = threadIdx.x;
  const int ol = tid >> 3;
  const int seg = tid & 7;
  const int t = blockIdx.x * 32 + ol;
  const int b = t >> 9, co = t & 511;
  const float* gr = g + b * 1024 + seg * 128;
  const float* wr = w7 + (size_t)co * 1216 + seg * 128;
  float a0 = 0.f, a1 = 0.f, a2 = 0.f, a3 = 0.f;
#pragma unroll 8
  for (int ci = 0; ci < 128; ci += 4) {
    float4 wv = *reinterpret_cast<const float4*>(wr + ci);
    float4 gv = *reinterpret_cast<const float4*>(gr + ci);
    a0 = fmaf(wv.x, gv.x, a0); a1 = fmaf(wv.y, gv.y, a1);
    a2 = fmaf(wv.z, gv.z, a2); a3 = fmaf(wv.w, gv.w, a3);
  }
  red[tid] = (a0 + a1) + (a2 + a3);
  __syncthreads();
  if (seg == 0) {
    float s = red[tid];
#pragma unroll
    for (int q = 1; q < 8; q++) s += red[tid + q];
    gcv[t] = s;
  }
}

// ---------------- conv7 v2: conv8-style tiled GEMM + gcv-init epilogue ------
__global__ __launch_bounds__(256) void k_conv7(
    const float* __restrict__ x1, const float* __restrict__ x2, const float* __restrict__ x3,
    const float* __restrict__ gcv, const float* __restrict__ w7,
    const float* __restrict__ s7, const float* __restrict__ b7,
    float* __restrict__ h7, int bbase) {
  __shared__ float Wl[64 * 68];
  __shared__ float Xl[64 * 68];
  const int tid = threadIdx.x;
  const int cot = blockIdx.x & 7;
  const int nt = blockIdx.x >> 3;
  const int co0 = (tid & 15) * 4;
  const int n0 = (tid >> 4) * 4;
  const int sr = tid >> 2;
  const int sci = (tid & 3) * 16;
  float acc[4][4];
#pragma unroll
  for (int i = 0; i < 4; i++)
#pragma unroll
    for (int j = 0; j < 4; j++) acc[i][j] = 0.f;

  for (int cib = 0; cib < 3; cib++) {
    const float* xsel = cib == 0 ? x1 : cib == 1 ? x2 : x3;
    __syncthreads();
    {
      const float* ws_ = w7 + (size_t)(cot * 64 + sr) * 1216 + 1024 + cib * 64 + sci;
#pragma unroll
      for (int s = 0; s < 16; s += 4) {
        float4 v = *reinterpret_cast<const float4*>(ws_ + s);
        Wl[(sci + s) * 68 + sr] = v.x;
        Wl[(sci + s + 1) * 68 + sr] = v.y;
        Wl[(sci + s + 2) * 68 + sr] = v.z;
        Wl[(sci + s + 3) * 68 + sr] = v.w;
      }
      const float* xs = xsel + (size_t)(bbase * NPTS + nt * 64 + sr) * 64 + sci;
#pragma unroll
      for (int s = 0; s < 16; s += 4) {
        float4 v = *reinterpret_cast<const float4*>(xs + s);
        Xl[(sci + s) * 68 + sr] = v.x;
        Xl[(sci + s + 1) * 68 + sr] = v.y;
        Xl[(sci + s + 2) * 68 + sr] = v.z;
        Xl[(sci + s + 3) * 68 + sr] = v.w;
      }
    }
    __syncthreads();
#pragma unroll 8
    for (int ci = 0; ci < 64; ci++) {
      float4 wv = *reinterpret_cast<const float4*>(&Wl[ci * 68 + co0]);
      float4 xv = *reinterpret_cast<const float4*>(&Xl[ci * 68 + n0]);
      acc[0][0] = fmaf(wv.x, xv.x, acc[0][0]);
      acc[0][1] = fmaf(wv.x, xv.y, acc[0][1]);
      acc[0][2] = fmaf(wv.x, xv.z, acc[0][2]);
      acc[0][3] = fmaf(wv.x, xv.w, acc[0][3]);
      acc[1][0] = fmaf(wv.y, xv.x, acc[1][0]);
      acc[1][1] = fmaf(wv.y, xv.y, acc[1][1]);
      acc[1][2] = fmaf(wv.y, xv.z, acc[1][2]);
      acc[1][3] = fmaf(wv.y, xv.w, acc[1][3]);
      acc[2][0] = fmaf(wv.z, xv.x, acc[2][0]);
      acc[2][1] = fmaf(wv.z, xv.y, acc[2][1]);
      acc[2][2] = fmaf(wv.z, xv.z, acc[2][2]);
      acc[2][3] = fmaf(wv.z, xv.w, acc[2][3]);
      acc[3][0] = fmaf(wv.w, xv.x, acc[3][0]);
      acc[3][1] = fmaf(wv.w, xv.y, acc[3][1]);
      acc[3][2] = fmaf(wv.w, xv.z, acc[3][2]);
      acc[3][3] = fmaf(wv.w, xv.w, acc[3][3]);
    }
  }
  const int b = bbase + (nt >> 6);
  float scv[4], bcv[4], g0v[4];
#pragma unroll
  for (int i = 0; i < 4; i++) {
    scv[i] = s7[cot * 64 + co0 + i];
    bcv[i] = b7[cot * 64 + co0 + i];
    g0v[i] = gcv[b * 512 + cot * 64 + co0 + i];
  }
#pragma unroll
  for (int j = 0; j < 4; j++) {
    float4 o;
    o.x = lrelu(fmaf(acc[0][j] + g0v[0], scv[0], bcv[0]));
    o.y = lrelu(fmaf(acc[1][j] + g0v[1], scv[1], bcv[1]));
    o.z = lrelu(fmaf(acc[2][j] + g0v[2], scv[2], bcv[2]));
    o.w = lrelu(fmaf(acc[3][j] + g0v[3], scv[3], bcv[3]));
    *reinterpret_cast<float4*>(
        &h7[(size_t)(nt * 64 + n0 + j) * 512 + cot * 64 + co0]) = o;
  }
}

// conv8: tiled GEMM 64n x 64co, ci-chunk 64 through LDS; two passes
__global__ __launch_bounds__(256) void k_conv8(
    const float* __restrict__ h7, const float* __restrict__ w8,
    const float* __restrict__ s8, const float* __restrict__ b8,
    float* __restrict__ h8, int bbase) {
  __shared__ float Wl[64 * 68];
  __shared__ float Xl[64 * 68];
  const int tid = threadIdx.x;
  const int cot = blockIdx.x & 3;
  const int nt = blockIdx.x >> 2;
  const int co0 = (tid & 15) * 4;
  const int n0 = (tid >> 4) * 4;
  const int sr = tid >> 2;
  const int sci = (tid & 3) * 16;
  float acc[4][4];
#pragma unroll
  for (int i = 0; i < 4; i++)
#pragma unroll
    for (int j = 0; j < 4; j++) acc[i][j] = 0.f;

  for (int cib = 0; cib < 512; cib += 64) {
    __syncthreads();
    {
      const float* ws_ = w8 + (size_t)(cot * 64 + sr) * 512 + cib + sci;
#pragma unroll
      for (int s = 0; s < 16; s += 4) {
        float4 v = *reinterpret_cast<const float4*>(ws_ + s);
        Wl[(sci + s) * 68 + sr] = v.x;
        Wl[(sci + s + 1) * 68 + sr] = v.y;
        Wl[(sci + s + 2) * 68 + sr] = v.z;
        Wl[(sci + s + 3) * 68 + sr] = v.w;
      }
      const float* xs = h7 + (size_t)(nt * 64 + sr) * 512 + cib + sci;
#pragma unroll
      for (int s = 0; s < 16; s += 4) {
        float4 v = *reinterpret_cast<const float4*>(xs + s);
        Xl[(sci + s) * 68 + sr] = v.x;
        Xl[(sci + s + 1) * 68 + sr] = v.y;
        Xl[(sci + s + 2) * 68 + sr] = v.z;
        Xl[(sci + s + 3) * 68 + sr] = v.w;
      }
    }
    __syncthreads();
#pragma unroll 8
    for (int ci = 0; ci < 64; ci++) {
      float4 wv = *reinterpret_cast<const float4*>(&Wl[ci * 68 + co0]);
      float4 xv = *reinterpret_cast<const float4*>(&Xl[ci * 68 + n0]);
      acc[0][0] = fmaf(wv.x, xv.x, acc[0][0]);
      acc[0][1] = fmaf(wv.x, xv.y, acc[0][1]);
      acc[0][2] = fmaf(wv.x, xv.z, acc[0][2]);
      acc[0][3] = fmaf(wv.x, xv.w, acc[0][3]);
      acc[1][0] = fmaf(wv.y, xv.x, acc[1][0]);
      acc[1][1] = fmaf(wv.y, xv.y, acc[1][1]);
      acc[1][2] = fmaf(wv.y, xv.z, acc[1][2]);
      acc[1][3] = fmaf(wv.y, xv.w, acc[1][3]);
      acc[2][0] = fmaf(wv.z, xv.x, acc[2][0]);
      acc[2][1] = fmaf(wv.z, xv.y, acc[2][1]);
      acc[2][2] = fmaf(wv.z, xv.z, acc[2][2]);
      acc[2][3] = fmaf(wv.z, xv.w, acc[2][3]);
      acc[3][0] = fmaf(wv.w, xv.x, acc[3][0]);
      acc[3][1] = fmaf(wv.w, xv.y, acc[3][1]);
      acc[3][2] = fmaf(wv.w, xv.z, acc[3][2]);
      acc[3][3] = fmaf(wv.w, xv.w, acc[3][3]);
    }
  }
  float scv[4], bcv[4];
#pragma unroll
  for (int i = 0; i < 4; i++) {
    scv[i] = s8[cot * 64 + co0 + i];
    bcv[i] = b8[cot * 64 + co0 + i];
  }
#pragma unroll
  for (int j = 0; j < 4; j++) {
    float4 o;
    o.x = lrelu(fmaf(acc[0][j], scv[0], bcv[0]));
    o.y = lrelu(fmaf(acc[1][j], scv[1], bcv[1]));
    o.z = lrelu(fmaf(acc[2][j], scv[2], bcv[2]));
    o.w = lrelu(fmaf(acc[3][j], scv[3], bcv[3]));
    *reinterpret_cast<float4*>(
        &h8[(size_t)(bbase * NPTS + nt * 64 + n0 + j) * 256 + cot * 64 + co0]) = o;
  }
}

// conv9: 256 -> 13 (+bias), writes (B,13,N) channel-major output
__global__ __launch_bounds__(256) void k_conv9(const float* __restrict__ h8,
                                               const float* __restrict__ w9,
                                               const float* __restrict__ b9,
                                               float* __restrict__ outp) {
  __shared__ float Wl[16 * 256];
  __shared__ float Xl[64 * 68];
  const int tid = threadIdx.x;
  for (int q = tid; q < 16 * 256; q += 256) Wl[q] = q < 13 * 256 ? w9[q] : 0.f;
  const int p = tid & 63, cg = tid >> 6;
  const int sr = tid >> 2, sci = (tid & 3) * 16;
  float acc[4] = {0.f, 0.f, 0.f, 0.f};
  for (int cib = 0; cib < 256; cib += 64) {
    __syncthreads();
    {
      const float* xs = h8 + (size_t)(blockIdx.x * 64 + sr) * 256 + cib + sci;
#pragma unroll
      for (int s = 0; s < 16; s += 4) {
        float4 v = *reinterpret_cast<const float4*>(xs + s);
        Xl[(sci + s) * 68 + sr] = v.x;
        Xl[(sci + s + 1) * 68 + sr] = v.y;
        Xl[(sci + s + 2) * 68 + sr] = v.z;
        Xl[(sci + s + 3) * 68 + sr] = v.w;
      }
    }
    __syncthreads();
#pragma unroll 8
    for (int ci = 0; ci < 64; ci++) {
      float xv = Xl[ci * 68 + p];
#pragma unroll
      for (int q = 0; q < 4; q++)
        acc[q] = fmaf(Wl[(cg * 4 + q) * 256 + cib + ci], xv, acc[q]);
    }
  }
  const int pg = blockIdx.x * 64 + p;
  const int bb = pg >> 12, n = pg & (NPTS - 1);
#pragma unroll
  for (int q = 0; q < 4; q++) {
    int co = cg * 4 + q;
    if (co < 13) outp[(size_t)(bb * 13 + co) * NPTS + n] = acc[q] + b9[co];
  }
}

// ---------------- launch ----------------
extern "C" void kernel_launch(void* const* d_in, const int* in_sizes, int n_in,
                              void* d_out, int out_size, void* d_ws, size_t ws_size,
                              hipStream_t stream) {
  const float* x = (const float*)d_in[0];
  const float* w1 = (const float*)d_in[1];
  const float* s1 = (const float*)d_in[2];
  const float* b1 = (const float*)d_in[3];
  const float* w2 = (const float*)d_in[4];
  const float* s2 = (const float*)d_in[5];
  const float* b2 = (const float*)d_in[6];
  const float* w3 = (const float*)d_in[7];
  const float* s3 = (const float*)d_in[8];
  const float* b3 = (const float*)d_in[9];
  const float* w4 = (const float*)d_in[10];
  const float* s4 = (const float*)d_in[11];
  const float* b4 = (const float*)d_in[12];
  const float* w5 = (const float*)d_in[13];
  const float* s5 = (const float*)d_in[14];
  const float* b5 = (const float*)d_in[15];
  const float* w6 = (const float*)d_in[16];
  const float* s6 = (const float*)d_in[17];
  const float* b6 = (const float*)d_in[18];
  const float* w7 = (const float*)d_in[19];
  const float* s7 = (const float*)d_in[20];
  const float* b7 = (const float*)d_in[21];
  const float* w8 = (const float*)d_in[22];
  const float* s8 = (const float*)d_in[23];
  const float* b8 = (const float*)d_in[24];
  const float* w9 = (const float*)d_in[25];
  const float* b9 = (const float*)d_in[26];

  float* ws = (float*)d_ws;
  float* xxp = ws + 0;               // 16384
  int* idxp = (int*)(ws + 16384);    // 327680
  int* flg = (int*)(ws + 344064);    // 16384
  float* x1 = ws + 360448;           // 1048576
  float* x2 = ws + 1409024;          // 1048576
  float* x3 = ws + 2457600;          // 1048576
  float* gpart = ws + 3506176;       // 131072
  float* g = ws + 3637248;           // 4096
  float* gcv = ws + 3641344;         // 2048
  float* h7 = ws + 3643392;          // 4194304 (half: 2 batches)
  float* h8 = ws + 7837696;          // 4194304
  // total: 12032000 floats = 48.1 MB

  // stage 1
  k_sq<6><<<64, 256, 0, stream>>>(x, xxp);
  k_knn6<<<2048, 512, 0, stream>>>(x, xxp, idxp, flg);
  k_knn_fix<6><<<512, 64, 0, stream>>>(x, xxp, idxp, flg);
  k_ec1<<<512, 256, 0, stream>>>(x, idxp, w1, s1, b1, w2, s2, b2, x1);
  // stage 2
  k_sq<64><<<64, 256, 0, stream>>>(x1, xxp);
  k_knn64<<<512, 512, 0, stream>>>(x1, xxp, idxp, flg);
  k_knn_fix<64><<<512, 64, 0, stream>>>(x1, xxp, idxp, flg);
  k_ec2<true><<<512, 256, 0, stream>>>(x1, idxp, w3, s3, b3, w4, s4, b4, x2);
  // stage 3
  k_sq<64><<<64, 256, 0, stream>>>(x2, xxp);
  k_knn64<<<512, 512, 0, stream>>>(x2, xxp, idxp, flg);
  k_knn_fix<64><<<512, 64, 0, stream>>>(x2, xxp, idxp, flg);
  k_ec2<false><<<512, 256, 0, stream>>>(x2, idxp, w5, s5, b5, nullptr, nullptr, nullptr, x3);
  // global feature
  k_conv6<<<2048, 256, 0, stream>>>(x1, x2, x3, w6, s6, b6, gpart);
  k_gred<<<16, 256, 0, stream>>>(gpart, g);
  k_gc<<<64, 256, 0, stream>>>(w7, g, gcv);
  // head, two batch-pair passes to halve h7 footprint
  for (int bbase = 0; bbase < NB; bbase += 2) {
    k_conv7<<<1024, 256, 0, stream>>>(x1, x2, x3, gcv, w7, s7, b7, h7, bbase);
    k_conv8<<<512, 256, 0, stream>>>(h7, w8, s8, b8, h8, bbase);
  }
  k_conv9<<<256, 256, 0, stream>>>(h8, w9, b9, (float*)d_out);
}

// Round 15
// 1784.144 us; speedup vs baseline: 1.1027x; 1.1027x over previous
//
#include <hip/hip_runtime.h>
#include <hip/hip_bf16.h>
#include <cstdint>
#include <cstddef>

#define NB 4
#define NPTS 4096
#define KK 20

typedef unsigned int u32;
typedef unsigned long long u64;

__device__ __forceinline__ float lrelu(float v) { return v >= 0.f ? v : 0.2f * v; }

// monotone map: larger float -> larger u32 (total order, handles negatives)
__device__ __forceinline__ u32 fmap(float f) {
  u32 u = __float_as_uint(f);
  return (int)u < 0 ? ~u : (u | 0x80000000u);
}

__device__ __forceinline__ u64 wmax64(u64 v) {
#pragma unroll
  for (int o = 32; o >= 1; o >>= 1) {
    u64 t = __shfl_xor(v, o, 64);
    v = t > v ? t : v;
  }
  return v;
}

// ---------------- squared norms ----------------
template <int C>
__global__ void k_sq(const float* __restrict__ f, float* __restrict__ xx) {
  int p = blockIdx.x * 256 + threadIdx.x;
  const float* fp = f + (size_t)p * C;
  float s = 0.f;
  if constexpr ((C & 3) == 0) {
#pragma unroll
    for (int c = 0; c < C; c += 4) {
      float4 v = *reinterpret_cast<const float4*>(fp + c);
      s += v.x * v.x + v.y * v.y + v.z * v.z + v.w * v.w;
    }
  } else {
#pragma unroll
    for (int c = 0; c < C; c++) s += fp[c] * fp[c];
  }
  xx[p] = s;
}

// ---------------- knn C=6: 8 waves/block, one row per wave ----------------
__global__ __launch_bounds__(512) void k_knn6(const float* __restrict__ f,
                                              const float* __restrict__ xx,
                                              int* __restrict__ idxo,
                                              int* __restrict__ flg) {
  __shared__ float chunkl[6 * 65];
  const int tid = threadIdx.x, wv = tid >> 6, lane = tid & 63;
  const int row = blockIdx.x * 8 + wv;
  const int b = row >> 12;
  const float xi = xx[row];

  float y[6];
#pragma unroll
  for (int c = 0; c < 6; c++) y[c] = f[(size_t)row * 6 + c];

  u64 t0 = 0, t1 = 0, t2 = 0, t3 = 0;

  for (int jc = 0; jc < NPTS / 64; jc++) {
    __syncthreads();
    for (int t = tid; t < 64 * 6; t += 512) {
      int j = t / 6, c = t - j * 6;
      chunkl[c * 65 + j] = f[(size_t)(b * NPTS + jc * 64 + j) * 6 + c];
    }
    __syncthreads();
    const float xj = xx[b * NPTS + jc * 64 + lane];
    float acc = 0.f;
#pragma unroll
    for (int c = 0; c < 6; c++) acc = fmaf(chunkl[c * 65 + lane], y[c], acc);
    const float s = fmaf(2.f, acc, -xi) - xj;
    const u64 key = ((u64)fmap(s) << 32) | (u64)(~(u32)(jc * 64 + lane));
    if (key > t3) {
      u64 a0 = t0, a1 = t1, a2 = t2;
      bool g0 = key > a0, g1 = key > a1, g2 = key > a2;
      t0 = g0 ? key : a0;
      t1 = g0 ? a0 : (g1 ? key : a1);
      t2 = g1 ? a1 : (g2 ? key : a2);
      t3 = g2 ? a2 : key;
    }
  }

  u64 h = t0, n1 = t1, n2 = t2, n3 = t3;
  int pops = 0, myj = 0;
  for (int m = 0; m < KK; m++) {
    u64 wm = wmax64(h);
    int j = (int)(~(u32)wm) & (NPTS - 1);
    if (lane == m) myj = j;
    if (h == wm) { h = n1; n1 = n2; n2 = n3; n3 = 0; pops++; }
  }
  u64 bad = __ballot(pops >= 4);
  if (lane < KK) idxo[(size_t)row * KK + lane] = myj;
  if (lane == 0) flg[row] = (bad != 0ull) ? 1 : 0;
}

// ---------------- knn C=64 v12 (best measured: 299us, r13; plateau family
// v9=313 v11=292 v12=299 v13=393 -- VALU-issue bound at 4 waves/SIMD, all
// counter-visible pathologies eliminated: 0 conflicts, 0 spills). ---------
__global__ __launch_bounds__(512, 2) void k_knn64(const float* __restrict__ f,
                                                  const float* __restrict__ xx,
                                                  int* __restrict__ idxo,
                                                  int* __restrict__ flg) {
  __shared__ float ch[4][64 * 68];
  const int tid = threadIdx.x, wv = tid >> 6, lane = tid & 63;
  const int rowbase = blockIdx.x * 32;
  const int b = rowbase >> 12;
  const float* fb = f + (size_t)b * NPTS * 64;
  const int r0 = rowbase + wv * 4;
  const float* yrow = f + (size_t)r0 * 64;  // 4 contiguous rows, wave-uniform

  float xi[4];
#pragma unroll
  for (int r = 0; r < 4; r++) xi[r] = xx[r0 + r];

  u64 t0[4], t1[4], t2[4], t3[4];
#pragma unroll
  for (int r = 0; r < 4; r++) { t0[r] = 0; t1[r] = 0; t2[r] = 0; t3[r] = 0; }

#pragma unroll 1
  for (int jp = 0; jp < NPTS / 256; jp++) {
    // stage superchunk (256 candidates x 64 ch): 8 float4 per thread
#pragma unroll 1
    for (int k = 0; k < 8; k++) {
      int flat = k * 512 + tid;  // 0..4095 float4s
      int row = flat >> 4, q = flat & 15;
      float4 v = *reinterpret_cast<const float4*>(
          fb + (size_t)(jp * 256 + row) * 64 + 4 * q);
      *reinterpret_cast<float4*>(&ch[row >> 6][(row & 63) * 68 + 4 * q]) = v;
    }
    __syncthreads();

    float acc[4][4];
#pragma unroll
    for (int r = 0; r < 4; r++)
#pragma unroll
      for (int u = 0; u < 4; u++) acc[r][u] = 0.f;
#pragma unroll 2
    for (int q = 0; q < 16; q++) {
      const float4 c0 = *reinterpret_cast<const float4*>(&ch[0][lane * 68 + 4 * q]);
      const float4 c1 = *reinterpret_cast<const float4*>(&ch[1][lane * 68 + 4 * q]);
      const float4 c2 = *reinterpret_cast<const float4*>(&ch[2][lane * 68 + 4 * q]);
      const float4 c3 = *reinterpret_cast<const float4*>(&ch[3][lane * 68 + 4 * q]);
#pragma unroll
      for (int r = 0; r < 4; r++) {
        const float4 yq = *reinterpret_cast<const float4*>(yrow + r * 64 + 4 * q);
        acc[r][0] = fmaf(c0.x, yq.x, acc[r][0]);
        acc[r][0] = fmaf(c0.y, yq.y, acc[r][0]);
        acc[r][0] = fmaf(c0.z, yq.z, acc[r][0]);
        acc[r][0] = fmaf(c0.w, yq.w, acc[r][0]);
        acc[r][1] = fmaf(c1.x, yq.x, acc[r][1]);
        acc[r][1] = fmaf(c1.y, yq.y, acc[r][1]);
        acc[r][1] = fmaf(c1.z, yq.z, acc[r][1]);
        acc[r][1] = fmaf(c1.w, yq.w, acc[r][1]);
        acc[r][2] = fmaf(c2.x, yq.x, acc[r][2]);
        acc[r][2] = fmaf(c2.y, yq.y, acc[r][2]);
        acc[r][2] = fmaf(c2.z, yq.z, acc[r][2]);
        acc[r][2] = fmaf(c2.w, yq.w, acc[r][2]);
        acc[r][3] = fmaf(c3.x, yq.x, acc[r][3]);
        acc[r][3] = fmaf(c3.y, yq.y, acc[r][3]);
        acc[r][3] = fmaf(c3.z, yq.z, acc[r][3]);
        acc[r][3] = fmaf(c3.w, yq.w, acc[r][3]);
      }
    }
    float xj[4];
    u32 jv[4];
#pragma unroll
    for (int u = 0; u < 4; u++) {
      xj[u] = xx[b * NPTS + jp * 256 + u * 64 + lane];
      jv[u] = ~(u32)(jp * 256 + u * 64 + lane);
    }
#pragma unroll
    for (int r = 0; r < 4; r++) {
#pragma unroll
      for (int u = 0; u < 4; u++) {
        const float s = fmaf(2.f, acc[r][u], -xi[r]) - xj[u];
        const u64 key = ((u64)fmap(s) << 32) | (u64)jv[u];
        if (key > t3[r]) {
          u64 a0 = t0[r], a1 = t1[r], a2 = t2[r];
          bool g0 = key > a0, g1 = key > a1, g2 = key > a2;
          t0[r] = g0 ? key : a0;
          t1[r] = g0 ? a0 : (g1 ? key : a1);
          t2[r] = g1 ? a1 : (g2 ? key : a2);
          t3[r] = g2 ? a2 : key;
        }
      }
    }
    __syncthreads();
  }

#pragma unroll
  for (int r = 0; r < 4; r++) {
    u64 h = t0[r], n1 = t1[r], n2 = t2[r], n3 = t3[r];
    int pops = 0, myj = 0;
    for (int m = 0; m < KK; m++) {
      u64 wm = wmax64(h);
      int j = (int)(~(u32)wm) & (NPTS - 1);
      if (lane == m) myj = j;
      if (h == wm) { h = n1; n1 = n2; n2 = n3; n3 = 0; pops++; }
    }
    u64 bad = __ballot(pops >= 4);
    if (lane < KK) idxo[(size_t)(r0 + r) * KK + lane] = myj;
    if (lane == 0) flg[r0 + r] = (bad != 0ull) ? 1 : 0;
  }
}

// rare exact fallback for flagged rows
template <int C>
__global__ __launch_bounds__(64) void k_knn_fix(const float* __restrict__ f,
                                                const float* __restrict__ xx,
                                                int* __restrict__ idxo,
                                                const int* __restrict__ flg) {
  __shared__ u64 kl[NPTS];
  const int lane = threadIdx.x;
  for (int row = blockIdx.x; row < NB * NPTS; row += gridDim.x) {
    if (!flg[row]) continue;
    const int b = row >> 12;
    float yreg[C];
#pragma unroll
    for (int c = 0; c < C; c++) yreg[c] = f[(size_t)row * C + c];
    const float xi = xx[row];
    for (int jj = 0; jj < 64; jj++) {
      int j = jj * 64 + lane;
      const float* fp = f + (size_t)(b * NPTS + j) * C;
      float d = 0.f;
#pragma unroll
      for (int c = 0; c < C; c++) d = fmaf(yreg[c], fp[c], d);
      float s = fmaf(2.f, d, -xi) - xx[b * NPTS + j];
      kl[j] = ((u64)fmap(s) << 32) | (u64)(u32)(~(u32)j);
    }
    __syncthreads();
    int myj = 0;
    for (int m = 0; m < KK; m++) {
      u64 lm = 0;
      for (int jj = 0; jj < 64; jj++) {
        u64 v = kl[jj * 64 + lane];
        lm = v > lm ? v : lm;
      }
      u64 wm = wmax64(lm);
      int j = (int)(~(u32)wm) & (NPTS - 1);
      if (lane == m) myj = j;
      if (lane == (j & 63)) kl[j] = 0;
      __syncthreads();
    }
    if (lane < KK) idxo[row * KK + lane] = myj;
    __syncthreads();
  }
}

// ---------------- edgeconv stage 1: 6 -> (12) -> 64 -> 64, max over K -------
// r13: 4 accumulation chains (dep latency halved) + next-k neighbor prefetch.
__global__ __launch_bounds__(256) void k_ec1(
    const float* __restrict__ x, const int* __restrict__ idx,
    const float* __restrict__ w1, const float* __restrict__ s1, const float* __restrict__ b1,
    const float* __restrict__ w2, const float* __restrict__ s2, const float* __restrict__ b2,
    float* __restrict__ out) {
  __shared__ float h1l[4][64];
  const int wv = threadIdx.x >> 6, lane = threadIdx.x & 63;
  float w1r[12];
#pragma unroll
  for (int c = 0; c < 12; c += 4) {
    float4 v = *reinterpret_cast<const float4*>(w1 + lane * 12 + c);
    w1r[c] = v.x; w1r[c + 1] = v.y; w1r[c + 2] = v.z; w1r[c + 3] = v.w;
  }
  float w2r[64];
#pragma unroll
  for (int c = 0; c < 64; c += 4) {
    float4 v = *reinterpret_cast<const float4*>(w2 + lane * 64 + c);
    w2r[c] = v.x; w2r[c + 1] = v.y; w2r[c + 2] = v.z; w2r[c + 3] = v.w;
  }
  const float sc1 = s1[lane], bc1 = b1[lane], sc2 = s2[lane], bc2 = b2[lane];
  const int wid = blockIdx.x * 4 + wv;
  for (int p = wid; p < NB * NPTS; p += 2048) {
    const float* cp = x + (size_t)p * 6;
    float c0 = cp[0], c1 = cp[1], c2 = cp[2], c3 = cp[3], c4 = cp[4], c5 = cp[5];
    const int bb = p >> 12;
    float m = -3.402823466e38f;
    int nb = idx[p * KK];
    float n0v[6];
    {
      const float* nf = x + (size_t)((bb << 12) + nb) * 6;
#pragma unroll
      for (int c = 0; c < 6; c++) n0v[c] = nf[c];
    }
    for (int k = 0; k < KK; k++) {
      float e0 = n0v[0] - c0, e1 = n0v[1] - c1, e2 = n0v[2] - c2;
      float e3 = n0v[3] - c3, e4 = n0v[4] - c4, e5 = n0v[5] - c5;
      if (k + 1 < KK) {
        int nb2 = idx[p * KK + k + 1];
        const float* nf = x + (size_t)((bb << 12) + nb2) * 6;
#pragma unroll
        for (int c = 0; c < 6; c++) n0v[c] = nf[c];
      }
      float h = w1r[0] * e0 + w1r[1] * e1 + w1r[2] * e2 + w1r[3] * e3 + w1r[4] * e4 +
                w1r[5] * e5 + w1r[6] * c0 + w1r[7] * c1 + w1r[8] * c2 + w1r[9] * c3 +
                w1r[10] * c4 + w1r[11] * c5;
      h = lrelu(fmaf(h, sc1, bc1));
      h1l[wv][lane] = h;
      float a0 = 0.f, a1 = 0.f, a2 = 0.f, a3 = 0.f;
#pragma unroll
      for (int c = 0; c < 64; c += 16) {
        float4 h0 = *reinterpret_cast<const float4*>(&h1l[wv][c]);
        float4 h1 = *reinterpret_cast<const float4*>(&h1l[wv][c + 4]);
        float4 h2 = *reinterpret_cast<const float4*>(&h1l[wv][c + 8]);
        float4 h3 = *reinterpret_cast<const float4*>(&h1l[wv][c + 12]);
        a0 = fmaf(w2r[c], h0.x, a0); a0 = fmaf(w2r[c + 1], h0.y, a0);
        a0 = fmaf(w2r[c + 2], h0.z, a0); a0 = fmaf(w2r[c + 3], h0.w, a0);
        a1 = fmaf(w2r[c + 4], h1.x, a1); a1 = fmaf(w2r[c + 5], h1.y, a1);
        a1 = fmaf(w2r[c + 6], h1.z, a1); a1 = fmaf(w2r[c + 7], h1.w, a1);
        a2 = fmaf(w2r[c + 8], h2.x, a2); a2 = fmaf(w2r[c + 9], h2.y, a2);
        a2 = fmaf(w2r[c + 10], h2.z, a2); a2 = fmaf(w2r[c + 11], h2.w, a2);
        a3 = fmaf(w2r[c + 12], h3.x, a3); a3 = fmaf(w2r[c + 13], h3.y, a3);
        a3 = fmaf(w2r[c + 14], h3.z, a3); a3 = fmaf(w2r[c + 15], h3.w, a3);
      }
      m = fmaxf(m, lrelu(fmaf((a0 + a1) + (a2 + a3), sc2, bc2)));
    }
    out[(size_t)p * 64 + lane] = m;
  }
}

// ---------------- edgeconv stages 2/3: 64 -> (128) -> 64 [-> 64], max over K
// r13: 4 accumulation chains + next-k neighbor-feature prefetch.
template <bool HAS2>
__global__ __launch_bounds__(256, 1) void k_ec2(
    const float* __restrict__ xin, const int* __restrict__ idx,
    const float* __restrict__ w3, const float* __restrict__ s3, const float* __restrict__ b3,
    const float* __restrict__ w4, const float* __restrict__ s4, const float* __restrict__ b4,
    float* __restrict__ out) {
  __shared__ float ctl[4][64];
  __shared__ float nbl[4][64];
  __shared__ float h1l[4][64];
  const int wv = threadIdx.x >> 6, lane = threadIdx.x & 63;
  float wa[64], wb[64];
#pragma unroll
  for (int c = 0; c < 64; c += 4) {
    float4 va = *reinterpret_cast<const float4*>(w3 + (size_t)lane * 128 + c);
    float4 vb = *reinterpret_cast<const float4*>(w3 + (size_t)lane * 128 + 64 + c);
    wa[c] = va.x; wa[c + 1] = va.y; wa[c + 2] = va.z; wa[c + 3] = va.w;
    wb[c] = vb.x - va.x; wb[c + 1] = vb.y - va.y; wb[c + 2] = vb.z - va.z; wb[c + 3] = vb.w - va.w;
  }
  float w4r[64];
  if constexpr (HAS2) {
#pragma unroll
    for (int c = 0; c < 64; c += 4) {
      float4 v = *reinterpret_cast<const float4*>(w4 + (size_t)lane * 64 + c);
      w4r[c] = v.x; w4r[c + 1] = v.y; w4r[c + 2] = v.z; w4r[c + 3] = v.w;
    }
  }
  const float sc3 = s3[lane], bc3 = b3[lane];
  float sc4 = 0.f, bc4 = 0.f;
  if constexpr (HAS2) { sc4 = s4[lane]; bc4 = b4[lane]; }
  const int wid = blockIdx.x * 4 + wv;
  for (int p = wid; p < NB * NPTS; p += 2048) {
    const int bb = p >> 12;
    ctl[wv][lane] = xin[(size_t)p * 64 + lane];
    float d0 = 0.f, d1 = 0.f;
#pragma unroll
    for (int c = 0; c < 64; c += 8) {
      float4 cv = *reinterpret_cast<const float4*>(&ctl[wv][c]);
      float4 cw = *reinterpret_cast<const float4*>(&ctl[wv][c + 4]);
      d0 = fmaf(wb[c], cv.x, d0); d0 = fmaf(wb[c + 1], cv.y, d0);
      d0 = fmaf(wb[c + 2], cv.z, d0); d0 = fmaf(wb[c + 3], cv.w, d0);
      d1 = fmaf(wb[c + 4], cw.x, d1); d1 = fmaf(wb[c + 5], cw.y, d1);
      d1 = fmaf(wb[c + 6], cw.z, d1); d1 = fmaf(wb[c + 7], cw.w, d1);
    }
    const float cd = d0 + d1;
    float m = -3.402823466e38f;
    float cur = xin[(size_t)((bb << 12) + idx[p * KK]) * 64 + lane];
    for (int k = 0; k < KK; k++) {
      nbl[wv][lane] = cur;
      if (k + 1 < KK)
        cur = xin[(size_t)((bb << 12) + idx[p * KK + k + 1]) * 64 + lane];
      float a0 = cd, a1 = 0.f, a2 = 0.f, a3 = 0.f;
#pragma unroll
      for (int c = 0; c < 64; c += 16) {
        float4 n0 = *reinterpret_cast<const float4*>(&nbl[wv][c]);
        float4 n1 = *reinterpret_cast<const float4*>(&nbl[wv][c + 4]);
        float4 n2 = *reinterpret_cast<const float4*>(&nbl[wv][c + 8]);
        float4 n3 = *reinterpret_cast<const float4*>(&nbl[wv][c + 12]);
        a0 = fmaf(wa[c], n0.x, a0); a0 = fmaf(wa[c + 1], n0.y, a0);
        a0 = fmaf(wa[c + 2], n0.z, a0); a0 = fmaf(wa[c + 3], n0.w, a0);
        a1 = fmaf(wa[c + 4], n1.x, a1); a1 = fmaf(wa[c + 5], n1.y, a1);
        a1 = fmaf(wa[c + 6], n1.z, a1); a1 = fmaf(wa[c + 7], n1.w, a1);
        a2 = fmaf(wa[c + 8], n2.x, a2); a2 = fmaf(wa[c + 9], n2.y, a2);
        a2 = fmaf(wa[c + 10], n2.z, a2); a2 = fmaf(wa[c + 11], n2.w, a2);
        a3 = fmaf(wa[c + 12], n3.x, a3); a3 = fmaf(wa[c + 13], n3.y, a3);
        a3 = fmaf(wa[c + 14], n3.z, a3); a3 = fmaf(wa[c + 15], n3.w, a3);
      }
      float h = lrelu(fmaf((a0 + a1) + (a2 + a3), sc3, bc3));
      if constexpr (HAS2) {
        h1l[wv][lane] = h;
        float q0 = 0.f, q1 = 0.f, q2 = 0.f, q3 = 0.f;
#pragma unroll
        for (int c = 0; c < 64; c += 16) {
          float4 h0 = *reinterpret_cast<const float4*>(&h1l[wv][c]);
          float4 h1 = *reinterpret_cast<const float4*>(&h1l[wv][c + 4]);
          float4 h2 = *reinterpret_cast<const float4*>(&h1l[wv][c + 8]);
          float4 h3 = *reinterpret_cast<const float4*>(&h1l[wv][c + 12]);
          q0 = fmaf(w4r[c], h0.x, q0); q0 = fmaf(w4r[c + 1], h0.y, q0);
          q0 = fmaf(w4r[c + 2], h0.z, q0); q0 = fmaf(w4r[c + 3], h0.w, q0);
          q1 = fmaf(w4r[c + 4], h1.x, q1); q1 = fmaf(w4r[c + 5], h1.y, q1);
          q1 = fmaf(w4r[c + 6], h1.z, q1); q1 = fmaf(w4r[c + 7], h1.w, q1);
          q2 = fmaf(w4r[c + 8], h2.x, q2); q2 = fmaf(w4r[c + 9], h2.y, q2);
          q2 = fmaf(w4r[c + 10], h2.z, q2); q2 = fmaf(w4r[c + 11], h2.w, q2);
          q3 = fmaf(w4r[c + 12], h3.x, q3); q3 = fmaf(w4r[c + 13], h3.y, q3);
          q3 = fmaf(w4r[c + 14], h3.z, q3); q3 = fmaf(w4r[c + 15], h3.w, q3);
        }
        m = fmaxf(m, lrelu(fmaf((q0 + q1) + (q2 + q3), sc4, bc4)));
      } else {
        m = fmaxf(m, h);
      }
    }
    out[(size_t)p * 64 + lane] = m;
  }
}

// ---------------- conv6 v2: conv8-style tiled GEMM + max epilogue -----------
__global__ __launch_bounds__(256) void k_conv6(
    const float* __restrict__ x1, const float* __restrict__ x2, const float* __restrict__ x3,
    const float* __restrict__ w6, const float* __restrict__ s6, const float* __restrict__ b6,
    float* __restrict__ gpart) {
  __shared__ float Wl[64 * 68];
  __shared__ float Xl[64 * 68];
  __shared__ float mxl[16][64];
  const int tid = threadIdx.x;
  const int cot = blockIdx.x & 15;  // 16 co-tiles of 64
  const int ptb = blockIdx.x >> 4;  // 0..127, 128 pts each
  const int co0 = (tid & 15) * 4;
  const int n0 = (tid >> 4) * 4;
  const int sr = tid >> 2;
  const int sci = (tid & 3) * 16;
  float scv[4], bcv[4];
#pragma unroll
  for (int i = 0; i < 4; i++) {
    scv[i] = s6[cot * 64 + co0 + i];
    bcv[i] = b6[cot * 64 + co0 + i];
  }
  float mx[4];
#pragma unroll
  for (int i = 0; i < 4; i++) mx[i] = -3.402823466e38f;

  for (int half = 0; half < 2; half++) {
    float acc[4][4];
#pragma unroll
    for (int i = 0; i < 4; i++)
#pragma unroll
      for (int j = 0; j < 4; j++) acc[i][j] = 0.f;
    for (int cib = 0; cib < 3; cib++) {
      const float* xsel = cib == 0 ? x1 : cib == 1 ? x2 : x3;
      __syncthreads();
      {
        const float* ws_ = w6 + (size_t)(cot * 64 + sr) * 192 + cib * 64 + sci;
#pragma unroll
        for (int s = 0; s < 16; s += 4) {
          float4 v = *reinterpret_cast<const float4*>(ws_ + s);
          Wl[(sci + s) * 68 + sr] = v.x;
          Wl[(sci + s + 1) * 68 + sr] = v.y;
          Wl[(sci + s + 2) * 68 + sr] = v.z;
          Wl[(sci + s + 3) * 68 + sr] = v.w;
        }
        const float* xs = xsel + (size_t)(ptb * 128 + half * 64 + sr) * 64 + sci;
#pragma unroll
        for (int s = 0; s < 16; s += 4) {
          float4 v = *reinterpret_cast<const float4*>(xs + s);
          Xl[(sci + s) * 68 + sr] = v.x;
          Xl[(sci + s + 1) * 68 + sr] = v.y;
          Xl[(sci + s + 2) * 68 + sr] = v.z;
          Xl[(sci + s + 3) * 68 + sr] = v.w;
        }
      }
      __syncthreads();
#pragma unroll 8
      for (int ci = 0; ci < 64; ci++) {
        float4 wv = *reinterpret_cast<const float4*>(&Wl[ci * 68 + co0]);
        float4 xv = *reinterpret_cast<const float4*>(&Xl[ci * 68 + n0]);
        acc[0][0] = fmaf(wv.x, xv.x, acc[0][0]);
        acc[0][1] = fmaf(wv.x, xv.y, acc[0][1]);
        acc[0][2] = fmaf(wv.x, xv.z, acc[0][2]);
        acc[0][3] = fmaf(wv.x, xv.w, acc[0][3]);
        acc[1][0] = fmaf(wv.y, xv.x, acc[1][0]);
        acc[1][1] = fmaf(wv.y, xv.y, acc[1][1]);
        acc[1][2] = fmaf(wv.y, xv.z, acc[1][2]);
        acc[1][3] = fmaf(wv.y, xv.w, acc[1][3]);
        acc[2][0] = fmaf(wv.z, xv.x, acc[2][0]);
        acc[2][1] = fmaf(wv.z, xv.y, acc[2][1]);
        acc[2][2] = fmaf(wv.z, xv.z, acc[2][2]);
        acc[2][3] = fmaf(wv.z, xv.w, acc[2][3]);
        acc[3][0] = fmaf(wv.w, xv.x, acc[3][0]);
        acc[3][1] = fmaf(wv.w, xv.y, acc[3][1]);
        acc[3][2] = fmaf(wv.w, xv.z, acc[3][2]);
        acc[3][3] = fmaf(wv.w, xv.w, acc[3][3]);
      }
    }
#pragma unroll
    for (int i = 0; i < 4; i++)
#pragma unroll
      for (int j = 0; j < 4; j++)
        mx[i] = fmaxf(mx[i], lrelu(fmaf(acc[i][j], scv[i], bcv[i])));
  }
  __syncthreads();
#pragma unroll
  for (int i = 0; i < 4; i++) mxl[tid >> 4][co0 + i] = mx[i];
  __syncthreads();
  if (tid < 64) {
    float m = -3.402823466e38f;
#pragma unroll
    for (int g = 0; g < 16; g++) m = fmaxf(m, mxl[g][tid]);
    const int b = ptb >> 5, ch = ptb & 31;
    gpart[(size_t)(b * 32 + ch) * 1024 + cot * 64 + tid] = m;
  }
}

__global__ void k_gred(const float* __restrict__ gpart, float* __restrict__ g) {
  int t = blockIdx.x * 256 + threadIdx.x;
  int b = t >> 10, co = t & 1023;
  float m = -3.402823466e38f;
  for (int ch = 0; ch < 32; ch++) m = fmaxf(m, gpart[(size_t)(b * 32 + ch) * 1024 + co]);
  g[t] = m;
}

// gc[b][co] = sum_{ci<1024} w7[co][ci] * g[b][ci]; 64 blocks, 8-way ci split
__global__ __launch_bounds__(256) void k_gc(const float* __restrict__ w7,
                                            const float* __restrict__ g,
                                            float* __restrict__ gcv) {
  __shared__ float red[256];
  const int tid = threadIdx.x;
  const int ol = tid >> 3;
  const int seg = tid & 7;
  const int t = blockIdx.x * 32 + ol;
  const int b = t >> 9, co = t & 511;
  const float* gr = g + b * 1024 + seg * 128;
  const float* wr = w7 + (size_t)co * 1216 + seg * 128;
  float a0 = 0.f, a1 = 0.f, a2 = 0.f, a3 = 0.f;
#pragma unroll 8
  for (int ci = 0; ci < 128; ci += 4) {
    float4 wv = *reinterpret_cast<const float4*>(wr + ci);
    float4 gv = *reinterpret_cast<const float4*>(gr + ci);
    a0 = fmaf(wv.x, gv.x, a0); a1 = fmaf(wv.y, gv.y, a1);
    a2 = fmaf(wv.z, gv.z, a2); a3 = fmaf(wv.w, gv.w, a3);
  }
  red[tid] = (a0 + a1) + (a2 + a3);
  __syncthreads();
  if (seg == 0) {
    float s = red[tid];
#pragma unroll
    for (int q = 1; q < 8; q++) s += red[tid + q];
    gcv[t] = s;
  }
}

// ---------------- conv7 v2: conv8-style tiled GEMM + gcv-init epilogue ------
__global__ __launch_bounds__(256) void k_conv7(
    const float* __restrict__ x1, const float* __restrict__ x2, const float* __restrict__ x3,
    const float* __restrict__ gcv, const float* __restrict__ w7,
    const float* __restrict__ s7, const float* __restrict__ b7,
    float* __restrict__ h7, int bbase) {
  __shared__ float Wl[64 * 68];
  __shared__ float Xl[64 * 68];
  const int tid = threadIdx.x;
  const int cot = blockIdx.x & 7;
  const int nt = blockIdx.x >> 3;
  const int co0 = (tid & 15) * 4;
  const int n0 = (tid >> 4) * 4;
  const int sr = tid >> 2;
  const int sci = (tid & 3) * 16;
  float acc[4][4];
#pragma unroll
  for (int i = 0; i < 4; i++)
#pragma unroll
    for (int j = 0; j < 4; j++) acc[i][j] = 0.f;

  for (int cib = 0; cib < 3; cib++) {
    const float* xsel = cib == 0 ? x1 : cib == 1 ? x2 : x3;
    __syncthreads();
    {
      const float* ws_ = w7 + (size_t)(cot * 64 + sr) * 1216 + 1024 + cib * 64 + sci;
#pragma unroll
      for (int s = 0; s < 16; s += 4) {
        float4 v = *reinterpret_cast<const float4*>(ws_ + s);
        Wl[(sci + s) * 68 + sr] = v.x;
        Wl[(sci + s + 1) * 68 + sr] = v.y;
        Wl[(sci + s + 2) * 68 + sr] = v.z;
        Wl[(sci + s + 3) * 68 + sr] = v.w;
      }
      const float* xs = xsel + (size_t)(bbase * NPTS + nt * 64 + sr) * 64 + sci;
#pragma unroll
      for (int s = 0; s < 16; s += 4) {
        float4 v = *reinterpret_cast<const float4*>(xs + s);
        Xl[(sci + s) * 68 + sr] = v.x;
        Xl[(sci + s + 1) * 68 + sr] = v.y;
        Xl[(sci + s + 2) * 68 + sr] = v.z;
        Xl[(sci + s + 3) * 68 + sr] = v.w;
      }
    }
    __syncthreads();
#pragma unroll 8
    for (int ci = 0; ci < 64; ci++) {
      float4 wv = *reinterpret_cast<const float4*>(&Wl[ci * 68 + co0]);
      float4 xv = *reinterpret_cast<const float4*>(&Xl[ci * 68 + n0]);
      acc[0][0] = fmaf(wv.x, xv.x, acc[0][0]);
      acc[0][1] = fmaf(wv.x, xv.y, acc[0][1]);
      acc[0][2] = fmaf(wv.x, xv.z, acc[0][2]);
      acc[0][3] = fmaf(wv.x, xv.w, acc[0][3]);
      acc[1][0] = fmaf(wv.y, xv.x, acc[1][0]);
      acc[1][1] = fmaf(wv.y, xv.y, acc[1][1]);
      acc[1][2] = fmaf(wv.y, xv.z, acc[1][2]);
      acc[1][3] = fmaf(wv.y, xv.w, acc[1][3]);
      acc[2][0] = fmaf(wv.z, xv.x, acc[2][0]);
      acc[2][1] = fmaf(wv.z, xv.y, acc[2][1]);
      acc[2][2] = fmaf(wv.z, xv.z, acc[2][2]);
      acc[2][3] = fmaf(wv.z, xv.w, acc[2][3]);
      acc[3][0] = fmaf(wv.w, xv.x, acc[3][0]);
      acc[3][1] = fmaf(wv.w, xv.y, acc[3][1]);
      acc[3][2] = fmaf(wv.w, xv.z, acc[3][2]);
      acc[3][3] = fmaf(wv.w, xv.w, acc[3][3]);
    }
  }
  const int b = bbase + (nt >> 6);
  float scv[4], bcv[4], g0v[4];
#pragma unroll
  for (int i = 0; i < 4; i++) {
    scv[i] = s7[cot * 64 + co0 + i];
    bcv[i] = b7[cot * 64 + co0 + i];
    g0v[i] = gcv[b * 512 + cot * 64 + co0 + i];
  }
#pragma unroll
  for (int j = 0; j < 4; j++) {
    float4 o;
    o.x = lrelu(fmaf(acc[0][j] + g0v[0], scv[0], bcv[0]));
    o.y = lrelu(fmaf(acc[1][j] + g0v[1], scv[1], bcv[1]));
    o.z = lrelu(fmaf(acc[2][j] + g0v[2], scv[2], bcv[2]));
    o.w = lrelu(fmaf(acc[3][j] + g0v[3], scv[3], bcv[3]));
    *reinterpret_cast<float4*>(
        &h7[(size_t)(nt * 64 + n0 + j) * 512 + cot * 64 + co0]) = o;
  }
}

// conv8: tiled GEMM 64n x 64co, ci-chunk 64 through LDS; two passes
__global__ __launch_bounds__(256) void k_conv8(
    const float* __restrict__ h7, const float* __restrict__ w8,
    const float* __restrict__ s8, const float* __restrict__ b8,
    float* __restrict__ h8, int bbase) {
  __shared__ float Wl[64 * 68];
  __shared__ float Xl[64 * 68];
  const int tid = threadIdx.x;
  const int cot = blockIdx.x & 3;
  const int nt = blockIdx.x >> 2;
  const int co0 = (tid & 15) * 4;
  const int n0 = (tid >> 4) * 4;
  const int sr = tid >> 2;
  const int sci = (tid & 3) * 16;
  float acc[4][4];
#pragma unroll
  for (int i = 0; i < 4; i++)
#pragma unroll
    for (int j = 0; j < 4; j++) acc[i][j] = 0.f;

  for (int cib = 0; cib < 512; cib += 64) {
    __syncthreads();
    {
      const float* ws_ = w8 + (size_t)(cot * 64 + sr) * 512 + cib + sci;
#pragma unroll
      for (int s = 0; s < 16; s += 4) {
        float4 v = *reinterpret_cast<const float4*>(ws_ + s);
        Wl[(sci + s) * 68 + sr] = v.x;
        Wl[(sci + s + 1) * 68 + sr] = v.y;
        Wl[(sci + s + 2) * 68 + sr] = v.z;
        Wl[(sci + s + 3) * 68 + sr] = v.w;
      }
      const float* xs = h7 + (size_t)(nt * 64 + sr) * 512 + cib + sci;
#pragma unroll
      for (int s = 0; s < 16; s += 4) {
        float4 v = *reinterpret_cast<const float4*>(xs + s);
        Xl[(sci + s) * 68 + sr] = v.x;
        Xl[(sci + s + 1) * 68 + sr] = v.y;
        Xl[(sci + s + 2) * 68 + sr] = v.z;
        Xl[(sci + s + 3) * 68 + sr] = v.w;
      }
    }
    __syncthreads();
#pragma unroll 8
    for (int ci = 0; ci < 64; ci++) {
      float4 wv = *reinterpret_cast<const float4*>(&Wl[ci * 68 + co0]);
      float4 xv = *reinterpret_cast<const float4*>(&Xl[ci * 68 + n0]);
      acc[0][0] = fmaf(wv.x, xv.x, acc[0][0]);
      acc[0][1] = fmaf(wv.x, xv.y, acc[0][1]);
      acc[0][2] = fmaf(wv.x, xv.z, acc[0][2]);
      acc[0][3] = fmaf(wv.x, xv.w, acc[0][3]);
      acc[1][0] = fmaf(wv.y, xv.x, acc[1][0]);
      acc[1][1] = fmaf(wv.y, xv.y, acc[1][1]);
      acc[1][2] = fmaf(wv.y, xv.z, acc[1][2]);
      acc[1][3] = fmaf(wv.y, xv.w, acc[1][3]);
      acc[2][0] = fmaf(wv.z, xv.x, acc[2][0]);
      acc[2][1] = fmaf(wv.z, xv.y, acc[2][1]);
      acc[2][2] = fmaf(wv.z, xv.z, acc[2][2]);
      acc[2][3] = fmaf(wv.z, xv.w, acc[2][3]);
      acc[3][0] = fmaf(wv.w, xv.x, acc[3][0]);
      acc[3][1] = fmaf(wv.w, xv.y, acc[3][1]);
      acc[3][2] = fmaf(wv.w, xv.z, acc[3][2]);
      acc[3][3] = fmaf(wv.w, xv.w, acc[3][3]);
    }
  }
  float scv[4], bcv[4];
#pragma unroll
  for (int i = 0; i < 4; i++) {
    scv[i] = s8[cot * 64 + co0 + i];
    bcv[i] = b8[cot * 64 + co0 + i];
  }
#pragma unroll
  for (int j = 0; j < 4; j++) {
    float4 o;
    o.x = lrelu(fmaf(acc[0][j], scv[0], bcv[0]));
    o.y = lrelu(fmaf(acc[1][j], scv[1], bcv[1]));
    o.z = lrelu(fmaf(acc[2][j], scv[2], bcv[2]));
    o.w = lrelu(fmaf(acc[3][j], scv[3], bcv[3]));
    *reinterpret_cast<float4*>(
        &h8[(size_t)(bbase * NPTS + nt * 64 + n0 + j) * 256 + cot * 64 + co0]) = o;
  }
}

// conv9: 256 -> 13 (+bias), writes (B,13,N) channel-major output
__global__ __launch_bounds__(256) void k_conv9(const float* __restrict__ h8,
                                               const float* __restrict__ w9,
                                               const float* __restrict__ b9,
                                               float* __restrict__ outp) {
  __shared__ float Wl[16 * 256];
  __shared__ float Xl[64 * 68];
  const int tid = threadIdx.x;
  for (int q = tid; q < 16 * 256; q += 256) Wl[q] = q < 13 * 256 ? w9[q] : 0.f;
  const int p = tid & 63, cg = tid >> 6;
  const int sr = tid >> 2, sci = (tid & 3) * 16;
  float acc[4] = {0.f, 0.f, 0.f, 0.f};
  for (int cib = 0; cib < 256; cib += 64) {
    __syncthreads();
    {
      const float* xs = h8 + (size_t)(blockIdx.x * 64 + sr) * 256 + cib + sci;
#pragma unroll
      for (int s = 0; s < 16; s += 4) {
        float4 v = *reinterpret_cast<const float4*>(xs + s);
        Xl[(sci + s) * 68 + sr] = v.x;
        Xl[(sci + s + 1) * 68 + sr] = v.y;
        Xl[(sci + s + 2) * 68 + sr] = v.z;
        Xl[(sci + s + 3) * 68 + sr] = v.w;
      }
    }
    __syncthreads();
#pragma unroll 8
    for (int ci = 0; ci < 64; ci++) {
      float xv = Xl[ci * 68 + p];
#pragma unroll
      for (int q = 0; q < 4; q++)
        acc[q] = fmaf(Wl[(cg * 4 + q) * 256 + cib + ci], xv, acc[q]);
    }
  }
  const int pg = blockIdx.x * 64 + p;
  const int bb = pg >> 12, n = pg & (NPTS - 1);
#pragma unroll
  for (int q = 0; q < 4; q++) {
    int co = cg * 4 + q;
    if (co < 13) outp[(size_t)(bb * 13 + co) * NPTS + n] = acc[q] + b9[co];
  }
}

// ---------------- launch ----------------
extern "C" void kernel_launch(void* const* d_in, const int* in_sizes, int n_in,
                              void* d_out, int out_size, void* d_ws, size_t ws_size,
                              hipStream_t stream) {
  const float* x = (const float*)d_in[0];
  const float* w1 = (const float*)d_in[1];
  const float* s1 = (const float*)d_in[2];
  const float* b1 = (const float*)d_in[3];
  const float* w2 = (const float*)d_in[4];
  const float* s2 = (const float*)d_in[5];
  const float* b2 = (const float*)d_in[6];
  const float* w3 = (const float*)d_in[7];
  const float* s3 = (const float*)d_in[8];
  const float* b3 = (const float*)d_in[9];
  const float* w4 = (const float*)d_in[10];
  const float* s4 = (const float*)d_in[11];
  const float* b4 = (const float*)d_in[12];
  const float* w5 = (const float*)d_in[13];
  const float* s5 = (const float*)d_in[14];
  const float* b5 = (const float*)d_in[15];
  const float* w6 = (const float*)d_in[16];
  const float* s6 = (const float*)d_in[17];
  const float* b6 = (const float*)d_in[18];
  const float* w7 = (const float*)d_in[19];
  const float* s7 = (const float*)d_in[20];
  const float* b7 = (const float*)d_in[21];
  const float* w8 = (const float*)d_in[22];
  const float* s8 = (const float*)d_in[23];
  const float* b8 = (const float*)d_in[24];
  const float* w9 = (const float*)d_in[25];
  const float* b9 = (const float*)d_in[26];

  float* ws = (float*)d_ws;
  float* xxp = ws + 0;               // 16384
  int* idxp = (int*)(ws + 16384);    // 327680
  int* flg = (int*)(ws + 344064);    // 16384
  float* x1 = ws + 360448;           // 1048576
  float* x2 = ws + 1409024;          // 1048576
  float* x3 = ws + 2457600;          // 1048576
  float* gpart = ws + 3506176;       // 131072
  float* g = ws + 3637248;           // 4096
  float* gcv = ws + 3641344;         // 2048
  float* h7 = ws + 3643392;          // 4194304 (half: 2 batches)
  float* h8 = ws + 7837696;          // 4194304
  // total: 12032000 floats = 48.1 MB

  // stage 1
  k_sq<6><<<64, 256, 0, stream>>>(x, xxp);
  k_knn6<<<2048, 512, 0, stream>>>(x, xxp, idxp, flg);
  k_knn_fix<6><<<512, 64, 0, stream>>>(x, xxp, idxp, flg);
  k_ec1<<<512, 256, 0, stream>>>(x, idxp, w1, s1, b1, w2, s2, b2, x1);
  // stage 2
  k_sq<64><<<64, 256, 0, stream>>>(x1, xxp);
  k_knn64<<<512, 512, 0, stream>>>(x1, xxp, idxp, flg);
  k_knn_fix<64><<<512, 64, 0, stream>>>(x1, xxp, idxp, flg);
  k_ec2<true><<<512, 256, 0, stream>>>(x1, idxp, w3, s3, b3, w4, s4, b4, x2);
  // stage 3
  k_sq<64><<<64, 256, 0, stream>>>(x2, xxp);
  k_knn64<<<512, 512, 0, stream>>>(x2, xxp, idxp, flg);
  k_knn_fix<64><<<512, 64, 0, stream>>>(x2, xxp, idxp, flg);
  k_ec2<false><<<512, 256, 0, stream>>>(x2, idxp, w5, s5, b5, nullptr, nullptr, nullptr, x3);
  // global feature
  k_conv6<<<2048, 256, 0, stream>>>(x1, x2, x3, w6, s6, b6, gpart);
  k_gred<<<16, 256, 0, stream>>>(gpart, g);
  k_gc<<<64, 256, 0, stream>>>(w7, g, gcv);
  // head, two batch-pair passes to halve h7 footprint
  for (int bbase = 0; bbase < NB; bbase += 2) {
    k_conv7<<<1024, 256, 0, stream>>>(x1, x2, x3, gcv, w7, s7, b7, h7, bbase);
    k_conv8<<<512, 256, 0, stream>>>(h7, w8, s8, b8, h8, bbase);
  }
  k_conv9<<<256, 256, 0, stream>>>(h8, w9, b9, (float*)d_out);
}